// Round 10
// baseline (186.531 us; speedup 1.0000x reference)
//
#include <hip/hip_runtime.h>
#include <hip/hip_bf16.h>
#include <math.h>

#define D_DIM   4096
#define B_ROWS  4096
#define K_CODES 256
#define MARGIN  3.0      // |approx d2 - exact d2| <= ~1.5 worst-case; 3.0 window
#define BK      64
#define NITER   (D_DIM / BK)   // 64
#define MT      16             // rows per block

// output layout (f32 elements)
#define IDX_OFF   (B_ROWS * D_DIM)                 // 16777216
#define PROBS_OFF (IDX_OFF + B_ROWS)               // 16781312
#define LOSS_OFF  (PROBS_OFF + B_ROWS * K_CODES)   // 17829888

typedef __bf16 bf16x8 __attribute__((ext_vector_type(8)));
typedef float  f32x4  __attribute__((ext_vector_type(4)));

// ws: cbsw[1M] ushort (2 MB) | cc[256] f64
// cbsw layout (16x16x32 B-frag order): element (code k, col c) at ushort
//   (((c>>5)*16 + (k>>4))*64 + ((c>>3)&3)*16 + (k&15))*8 + (c&7)
// k-step L (32 dims) occupies ushorts [L*8192, L*8192+8192) covering all codes;
// within: ct*512 + lane*8 gives lane l 16 B = B[k=L*32+(l>>4)*8+j][code=ct*16+(l&15)]

static __device__ inline unsigned short f2bf(float f) {
    __hip_bfloat16 h = __float2bfloat16(f);
    return *reinterpret_cast<unsigned short*>(&h);
}

// ---------------------------------------------------------------------------
// prep_cb: one wave per codebook row. Swizzled bf16 codebook (16x16x32 frag
// order) + cc (f64 row sum of squares).
// ---------------------------------------------------------------------------
__global__ __launch_bounds__(64) void prep_cb(const float* __restrict__ cb,
                                              unsigned short* __restrict__ cbsw,
                                              double* __restrict__ cc) {
    const int lane = threadIdx.x & 63;
    const int k = blockIdx.x;                            // code 0..255
    const float4* row4 = (const float4*)(cb + (size_t)k * D_DIM);
    double a0 = 0.0, a1 = 0.0, a2 = 0.0, a3 = 0.0;
#pragma unroll
    for (int i = 0; i < 16; ++i) {
        float4 v = row4[i * 64 + lane];
        a0 += (double)v.x * v.x; a1 += (double)v.y * v.y;
        a2 += (double)v.z * v.z; a3 += (double)v.w * v.w;
        ushort4 h;
        h.x = f2bf(v.x); h.y = f2bf(v.y); h.z = f2bf(v.z); h.w = f2bf(v.w);
        const int c = (i * 64 + lane) * 4;               // col of this chunk
        const size_t idx = (((size_t)(c >> 5) * 16 + (k >> 4)) * 64
                            + ((c >> 3) & 3) * 16 + (k & 15)) * 8 + (c & 7);
        *(ushort4*)&cbsw[idx] = h;
    }
    double s = (a0 + a1) + (a2 + a3);
    for (int off = 32; off; off >>= 1) s += __shfl_xor(s, off);
    if (lane == 0) cc[k] = s;
}

// ---------------------------------------------------------------------------
// vq: fused full-K gemm + argmax + gather. 256 blocks x 512 threads (8 waves).
// Block = 16 rows x 256 codes x K=4096. BK=64, 64 tiles.
// B: global_load_lds DMA, TRIPLE-buffered (issue tile t+2 during tile t;
//    end-of-tile vmcnt(5) drains B(t+1), keeps B(t+2)x4 + A(t+2) in flight).
// A: 1 float2/thread/tile (uniform vmcnt), staged to LDS next tile.
// ---------------------------------------------------------------------------
__global__ __launch_bounds__(512) void vq(const float* __restrict__ x,
                                          const float* __restrict__ cb,
                                          const unsigned short* __restrict__ cbsw,
                                          const double* __restrict__ cc,
                                          float* __restrict__ out) {
    __shared__ unsigned short Bs[3][16384];  // 3 x 32 KB
    __shared__ unsigned short As[2][1024];   // 2 x 2 KB
    __shared__ float d2s[MT][K_CODES];       // 16 KB
    __shared__ float xxs[MT];
    const int t = threadIdx.x;
    const int lane = t & 63, w = t >> 6;     // 8 waves
    const int m0 = blockIdx.x * MT;

    // A: thread t -> row t>>5, k-cols (t&31)*2..+1 of each 64-k tile
    const int arow = t >> 5;                 // 0..15
    const int ak = (t & 31) * 2;             // 0..62
    const float2* ag2 = (const float2*)(x + (size_t)(m0 + arow) * D_DIM + ak);
    const int aw = (ak >> 3) * 128 + arow * 8 + (ak & 7);   // ushort idx
    // B frag read base (ushorts within a Bs buffer): + s*8192, +512 for odd ct
    const int brd = w * 1024 + lane * 8;

    f32x4 acc0 = {0.f, 0.f, 0.f, 0.f}, acc1 = {0.f, 0.f, 0.f, 0.f};
    float sq = 0.f;

    // ---- prologue: B(0)->Bs[0], B(1)->Bs[1]; A(0) staged; A(1)->cprev ----
#pragma unroll
    for (int r = 0; r < 4; ++r)
        __builtin_amdgcn_global_load_lds(
            (const __attribute__((address_space(1))) void*)(cbsw + r * 4096 + t * 8),
            (__attribute__((address_space(3))) void*)(&Bs[0][r * 4096 + t * 8]),
            16, 0, 0);
#pragma unroll
    for (int r = 0; r < 4; ++r)
        __builtin_amdgcn_global_load_lds(
            (const __attribute__((address_space(1))) void*)(cbsw + 16384 + r * 4096 + t * 8),
            (__attribute__((address_space(3))) void*)(&Bs[1][r * 4096 + t * 8]),
            16, 0, 0);
    float2 a0v   = ag2[0];
    float2 cprev = ag2[32];     // A(1): tile stride = 64 f32 = 32 float2
    {
        ushort2 hh; hh.x = f2bf(a0v.x); hh.y = f2bf(a0v.y);
        *(ushort2*)&As[0][aw] = hh;
        sq += a0v.x * a0v.x + a0v.y * a0v.y;
    }
    asm volatile("s_waitcnt vmcnt(1) lgkmcnt(0)" ::: "memory");
    __builtin_amdgcn_s_barrier();
    __builtin_amdgcn_sched_barrier(0);

    // ---- main loop: 64 tiles ----
    int bp_r = 0;
    for (int kt = 0; kt < NITER; ++kt) {
        const int p = kt & 1;
        const int bp_w = (bp_r >= 1) ? bp_r - 1 : 2;    // (bp_r+2)%3

        // 1. B-DMA tile kt+2 -> Bs[bp_w] (clamped; slot unread in tail)
        const int ktB = (kt + 2 < NITER) ? kt + 2 : 0;
        const unsigned short* src = cbsw + (size_t)ktB * 16384 + t * 8;
#pragma unroll
        for (int r = 0; r < 4; ++r)
            __builtin_amdgcn_global_load_lds(
                (const __attribute__((address_space(1))) void*)(src + r * 4096),
                (__attribute__((address_space(3))) void*)(&Bs[bp_w][r * 4096 + t * 8]),
                16, 0, 0);
        // 2. A-load tile kt+2 (issued AFTER B -> vmcnt(5) keeps it in flight)
        const int ktA = (kt + 2 < NITER) ? kt + 2 : 0;
        float2 cnew = ag2[(size_t)ktA * 32];

        // 3. MFMA on As[p], Bs[bp_r]
        __builtin_amdgcn_s_setprio(1);
#pragma unroll
        for (int s = 0; s < 2; ++s) {
            bf16x8 af = *(const bf16x8*)&As[p][(s * 64 + lane) * 8];
            bf16x8 b0 = *(const bf16x8*)&Bs[bp_r][s * 8192 + brd];
            bf16x8 b1 = *(const bf16x8*)&Bs[bp_r][s * 8192 + brd + 512];
            acc0 = __builtin_amdgcn_mfma_f32_16x16x32_bf16(af, b0, acc0, 0, 0, 0);
            acc1 = __builtin_amdgcn_mfma_f32_16x16x32_bf16(af, b1, acc1, 0, 0, 0);
        }
        __builtin_amdgcn_s_setprio(0);

        // 4. stage A(kt+1) (loaded last tile) into As[p^1]
        if (kt + 1 < NITER) {
            ushort2 hh; hh.x = f2bf(cprev.x); hh.y = f2bf(cprev.y);
            *(ushort2*)&As[p ^ 1][aw] = hh;
            sq += cprev.x * cprev.x + cprev.y * cprev.y;
        }

        // 5. drain B(kt+1) [older than this tile's 5 issues], publish, rotate
        asm volatile("s_waitcnt vmcnt(5) lgkmcnt(0)" ::: "memory");
        __builtin_amdgcn_s_barrier();
        __builtin_amdgcn_sched_barrier(0);
        cprev = cnew;
        bp_r = (bp_r < 2) ? bp_r + 1 : 0;
    }

    // ---- dots -> LDS; xx reduce (32 threads share a row) ----
#pragma unroll
    for (int r = 0; r < 4; ++r) {
        const int orow = (lane >> 4) * 4 + r;   // C/D: col=lane&15, row=(lane>>4)*4+r
        d2s[orow][w * 32 + (lane & 15)]      = acc0[r];
        d2s[orow][w * 32 + 16 + (lane & 15)] = acc1[r];
    }
    sq += __shfl_xor(sq, 1); sq += __shfl_xor(sq, 2); sq += __shfl_xor(sq, 4);
    sq += __shfl_xor(sq, 8); sq += __shfl_xor(sq, 16);
    if ((t & 31) == 0) xxs[arow] = sq;
    __syncthreads();

    // ---- per-wave argmax + margin + refine + write (rows w, w+8) ----
#pragma unroll
    for (int rr = 0; rr < 2; ++rr) {
        const int r = w + 8 * rr;
        const int row = m0 + r;
        const double xx = (double)xxs[r];
        const float4 dv = ((const float4*)&d2s[r][0])[lane];
        double v[4];
        v[0] = xx + cc[4 * lane + 0] - 2.0 * (double)dv.x;
        v[1] = xx + cc[4 * lane + 1] - 2.0 * (double)dv.y;
        v[2] = xx + cc[4 * lane + 2] - 2.0 * (double)dv.z;
        v[3] = xx + cc[4 * lane + 3] - 2.0 * (double)dv.w;

        double mx = fmax(fmax(v[0], v[1]), fmax(v[2], v[3]));
        for (int off = 32; off; off >>= 1) mx = fmax(mx, __shfl_xor(mx, off));
        const double thr = mx - MARGIN;

        unsigned long long b[4];
#pragma unroll
        for (int j = 0; j < 4; ++j) b[j] = __ballot(v[j] >= thr);
        const int total = __popcll(b[0]) + __popcll(b[1]) + __popcll(b[2]) + __popcll(b[3]);

        int bestk = 0; double best;
        if (total == 1) {
            best = mx;   // lone candidate IS the max
#pragma unroll
            for (int j = 0; j < 4; ++j)
                if (b[j]) bestk = 4 * (int)__builtin_ctzll(b[j]) + j;
        } else {
            const float4* xrow4 = (const float4*)(x + (size_t)row * D_DIM);
            int flags = 0;
#pragma unroll
            for (int j = 0; j < 4; ++j) if (v[j] >= thr) flags |= 1 << j;
            unsigned long long cand = __ballot(flags != 0);
            best = -1.0e300;
            while (cand) {
                const int lsrc = __builtin_ctzll(cand);
                cand &= cand - 1;
                const int f = __shfl(flags, lsrc);
                for (int j = 0; j < 4; ++j) {
                    if (!((f >> j) & 1)) continue;
                    const int k = 4 * lsrc + j;
                    const float4* crow4 = (const float4*)(cb + (size_t)k * D_DIM);
                    double a0 = 0.0, a1 = 0.0, a2 = 0.0, a3 = 0.0;
#pragma unroll
                    for (int i = 0; i < 16; ++i) {
                        float4 xa = xrow4[i * 64 + lane];
                        float4 ca = crow4[i * 64 + lane];
                        a0 += (double)xa.x * ca.x; a1 += (double)xa.y * ca.y;
                        a2 += (double)xa.z * ca.z; a3 += (double)xa.w * ca.w;
                    }
                    double s = (a0 + a1) + (a2 + a3);
                    for (int off = 32; off; off >>= 1) s += __shfl_xor(s, off);
                    const double d2e = xx + cc[k] - 2.0 * s;
                    if (d2e > best) { best = d2e; bestk = k; }
                }
            }
        }

        if (lane == 0) {
            out[IDX_OFF + row]  = (float)bestk;
            out[LOSS_OFF + row] = (float)(1.25 * best / (double)D_DIM);
        }
        float4 z = make_float4(0.f, 0.f, 0.f, 0.f);
        ((float4*)(out + PROBS_OFF + (size_t)row * K_CODES))[lane] = z;
        const float4* src = (const float4*)(cb + (size_t)bestk * D_DIM);
        float4* dst = (float4*)(out + (size_t)row * D_DIM);
#pragma unroll
        for (int i = 0; i < 16; ++i) dst[i * 64 + lane] = src[i * 64 + lane];
    }
}

// ---------------------------------------------------------------------------
extern "C" void kernel_launch(void* const* d_in, const int* in_sizes, int n_in,
                              void* d_out, int out_size, void* d_ws, size_t ws_size,
                              hipStream_t stream) {
    const float* x  = (const float*)d_in[0];
    const float* cb = (const float*)d_in[1];
    float* out = (float*)d_out;

    unsigned short* cbsw = (unsigned short*)d_ws;
    double*         cc   = (double*)((char*)d_ws + (size_t)K_CODES * D_DIM * sizeof(unsigned short));

    hipLaunchKernelGGL(prep_cb, dim3(256), dim3(64),  0, stream, cb, cbsw, cc);
    hipLaunchKernelGGL(vq,      dim3(256), dim3(512), 0, stream, x, cb, cbsw, cc, out);
}

// Round 11
// 163.246 us; speedup vs baseline: 1.1426x; 1.1426x over previous
//
#include <hip/hip_runtime.h>
#include <hip/hip_bf16.h>
#include <math.h>

#define D_DIM   4096
#define B_ROWS  4096
#define K_CODES 256
#define MARGIN  3.0      // |approx d2 - exact d2| <= ~1.5 worst-case; 3.0 window
#define MT      16             // rows per block
#define NSTEP   (D_DIM / 32)   // 128 k-steps of 32

// output layout (f32 elements)
#define IDX_OFF   (B_ROWS * D_DIM)                 // 16777216
#define PROBS_OFF (IDX_OFF + B_ROWS)               // 16781312
#define LOSS_OFF  (PROBS_OFF + B_ROWS * K_CODES)   // 17829888

typedef __bf16 bf16x8 __attribute__((ext_vector_type(8)));
typedef float  f32x4  __attribute__((ext_vector_type(4)));

// ws: cbsw[1M] ushort (2 MB) | cc[256] f64
// cbsw layout (16x16x32 B-frag order): element (code k, col c) at ushort
//   (((c>>5)*16 + (k>>4))*64 + ((c>>3)&3)*16 + (k&15))*8 + (c&7)
// k-step L occupies [L*8192, L*8192+8192) ushorts; wave w, tile ct in {2w,2w+1}:
//   lane l reads 16 B at L*8192 + ct*512 + l*8
//   = B[k = L*32 + (l>>4)*8 + j][code = ct*16 + (l&15)]

static __device__ inline unsigned short f2bf(float f) {
    __hip_bfloat16 h = __float2bfloat16(f);
    return *reinterpret_cast<unsigned short*>(&h);
}

// ---------------------------------------------------------------------------
// prep_cb: one wave per codebook row. Swizzled bf16 codebook (16x16x32 frag
// order) + cc (f64 row sum of squares).
// ---------------------------------------------------------------------------
__global__ __launch_bounds__(64) void prep_cb(const float* __restrict__ cb,
                                              unsigned short* __restrict__ cbsw,
                                              double* __restrict__ cc) {
    const int lane = threadIdx.x & 63;
    const int k = blockIdx.x;                            // code 0..255
    const float4* row4 = (const float4*)(cb + (size_t)k * D_DIM);
    double a0 = 0.0, a1 = 0.0, a2 = 0.0, a3 = 0.0;
#pragma unroll
    for (int i = 0; i < 16; ++i) {
        float4 v = row4[i * 64 + lane];
        a0 += (double)v.x * v.x; a1 += (double)v.y * v.y;
        a2 += (double)v.z * v.z; a3 += (double)v.w * v.w;
        ushort4 h;
        h.x = f2bf(v.x); h.y = f2bf(v.y); h.z = f2bf(v.z); h.w = f2bf(v.w);
        const int c = (i * 64 + lane) * 4;               // col of this chunk
        const size_t idx = (((size_t)(c >> 5) * 16 + (k >> 4)) * 64
                            + ((c >> 3) & 3) * 16 + (k & 15)) * 8 + (c & 7);
        *(ushort4*)&cbsw[idx] = h;
    }
    double s = (a0 + a1) + (a2 + a3);
    for (int off = 32; off; off >>= 1) s += __shfl_xor(s, off);
    if (lane == 0) cc[k] = s;
}

// ---------------------------------------------------------------------------
// vq v10: fused, ZERO-barrier K-loop. 256 blocks x 512 threads (8 waves).
// Block = 16 rows x 256 codes x full K=4096.
// Stage the ENTIRE A-tile (128 KB bf16) into LDS once (coalesced float4 +
// f2bf), ONE __syncthreads, then each wave independently streams 128 k-steps:
// ds_read_b128 A-frag + 2x16B global B-loads (cbsw L2-resident) + 2 MFMA.
// No barriers, no waitcnt asm, nothing the allocator can defeat.
// A-frag map identical to R7/R8-verified: ushort idx s*512 + lane*8 + j
//   <-> element (row = lane&15, k = s*32 + (lane>>4)*8 + j).
// ---------------------------------------------------------------------------
__global__ __launch_bounds__(512) void vq(const float* __restrict__ x,
                                          const float* __restrict__ cb,
                                          const unsigned short* __restrict__ cbsw,
                                          const double* __restrict__ cc,
                                          float* __restrict__ out) {
    __shared__ unsigned short As[NSTEP * 512];   // 128 KB full-K A tile
    __shared__ float d2s[MT][K_CODES];           // 16 KB
    __shared__ float xxs[MT];
    const int t = threadIdx.x;
    const int lane = t & 63, w = t >> 6;         // 8 waves
    const int m0 = blockIdx.x * MT;

    // ---- stage full A tile: thread t -> row t>>5, cols (t&31)*4 + 128*p ----
    const int arow = t >> 5;                     // 0..15
    const int ac0 = (t & 31) * 4;                // 0..124
    const float4* ag4 = (const float4*)(x + (size_t)(m0 + arow) * D_DIM + ac0);
    float sq = 0.f;
#pragma unroll
    for (int p = 0; p < 32; ++p) {
        float4 v = ag4[(size_t)p * 32];
        ushort4 h;
        h.x = f2bf(v.x); h.y = f2bf(v.y); h.z = f2bf(v.z); h.w = f2bf(v.w);
        const int c = ac0 + p * 128;
        // idx = (c>>5)*512 + (((c>>3)&3)*16 + row)*8 + (c&7)
        *(ushort4*)&As[(c >> 5) * 512 + (((c >> 3) & 3) * 16 + arow) * 8 + (c & 7)] = h;
        sq += v.x * v.x + v.y * v.y + v.z * v.z + v.w * v.w;
    }
    // xx reduce across the 32 threads sharing a row (lanes 0-31 / 32-63)
    sq += __shfl_xor(sq, 1); sq += __shfl_xor(sq, 2); sq += __shfl_xor(sq, 4);
    sq += __shfl_xor(sq, 8); sq += __shfl_xor(sq, 16);
    if ((t & 31) == 0) xxs[arow] = sq;
    __syncthreads();                             // the ONLY pre-epilogue barrier

    // ---- streaming K-loop: no barriers ----
    f32x4 acc0 = {0.f, 0.f, 0.f, 0.f}, acc1 = {0.f, 0.f, 0.f, 0.f};
    const unsigned short* bb = cbsw + w * 1024 + lane * 8;
    const unsigned short* ar = &As[lane * 8];
#pragma unroll 8
    for (int s = 0; s < NSTEP; ++s) {
        bf16x8 af = *(const bf16x8*)(ar + s * 512);
        bf16x8 b0 = *(const bf16x8*)(bb + (size_t)s * 8192);
        bf16x8 b1 = *(const bf16x8*)(bb + (size_t)s * 8192 + 512);
        acc0 = __builtin_amdgcn_mfma_f32_16x16x32_bf16(af, b0, acc0, 0, 0, 0);
        acc1 = __builtin_amdgcn_mfma_f32_16x16x32_bf16(af, b1, acc1, 0, 0, 0);
    }

    // ---- dots -> LDS ----
#pragma unroll
    for (int r = 0; r < 4; ++r) {
        const int orow = (lane >> 4) * 4 + r;    // C/D: col=lane&15, row=(lane>>4)*4+r
        d2s[orow][w * 32 + (lane & 15)]      = acc0[r];
        d2s[orow][w * 32 + 16 + (lane & 15)] = acc1[r];
    }
    __syncthreads();

    // ---- per-wave argmax + margin + refine + write (rows w, w+8) ----
#pragma unroll
    for (int rr = 0; rr < 2; ++rr) {
        const int r = w + 8 * rr;
        const int row = m0 + r;
        const double xx = (double)xxs[r];
        const float4 dv = ((const float4*)&d2s[r][0])[lane];
        double v[4];
        v[0] = xx + cc[4 * lane + 0] - 2.0 * (double)dv.x;
        v[1] = xx + cc[4 * lane + 1] - 2.0 * (double)dv.y;
        v[2] = xx + cc[4 * lane + 2] - 2.0 * (double)dv.z;
        v[3] = xx + cc[4 * lane + 3] - 2.0 * (double)dv.w;

        double mx = fmax(fmax(v[0], v[1]), fmax(v[2], v[3]));
        for (int off = 32; off; off >>= 1) mx = fmax(mx, __shfl_xor(mx, off));
        const double thr = mx - MARGIN;

        unsigned long long b[4];
#pragma unroll
        for (int j = 0; j < 4; ++j) b[j] = __ballot(v[j] >= thr);
        const int total = __popcll(b[0]) + __popcll(b[1]) + __popcll(b[2]) + __popcll(b[3]);

        int bestk = 0; double best;
        if (total == 1) {
            best = mx;   // lone candidate IS the max
#pragma unroll
            for (int j = 0; j < 4; ++j)
                if (b[j]) bestk = 4 * (int)__builtin_ctzll(b[j]) + j;
        } else {
            const float4* xrow4 = (const float4*)(x + (size_t)row * D_DIM);
            int flags = 0;
#pragma unroll
            for (int j = 0; j < 4; ++j) if (v[j] >= thr) flags |= 1 << j;
            unsigned long long cand = __ballot(flags != 0);
            best = -1.0e300;
            while (cand) {
                const int lsrc = __builtin_ctzll(cand);
                cand &= cand - 1;
                const int f = __shfl(flags, lsrc);
                for (int j = 0; j < 4; ++j) {
                    if (!((f >> j) & 1)) continue;
                    const int k = 4 * lsrc + j;
                    const float4* crow4 = (const float4*)(cb + (size_t)k * D_DIM);
                    double a0 = 0.0, a1 = 0.0, a2 = 0.0, a3 = 0.0;
#pragma unroll
                    for (int i = 0; i < 16; ++i) {
                        float4 xa = xrow4[i * 64 + lane];
                        float4 ca = crow4[i * 64 + lane];
                        a0 += (double)xa.x * ca.x; a1 += (double)xa.y * ca.y;
                        a2 += (double)xa.z * ca.z; a3 += (double)xa.w * ca.w;
                    }
                    double s = (a0 + a1) + (a2 + a3);
                    for (int off = 32; off; off >>= 1) s += __shfl_xor(s, off);
                    const double d2e = xx + cc[k] - 2.0 * s;
                    if (d2e > best) { best = d2e; bestk = k; }
                }
            }
        }

        if (lane == 0) {
            out[IDX_OFF + row]  = (float)bestk;
            out[LOSS_OFF + row] = (float)(1.25 * best / (double)D_DIM);
        }
        float4 z = make_float4(0.f, 0.f, 0.f, 0.f);
        ((float4*)(out + PROBS_OFF + (size_t)row * K_CODES))[lane] = z;
        const float4* src = (const float4*)(cb + (size_t)bestk * D_DIM);
        float4* dst = (float4*)(out + (size_t)row * D_DIM);
#pragma unroll
        for (int i = 0; i < 16; ++i) dst[i * 64 + lane] = src[i * 64 + lane];
    }
}

// ---------------------------------------------------------------------------
extern "C" void kernel_launch(void* const* d_in, const int* in_sizes, int n_in,
                              void* d_out, int out_size, void* d_ws, size_t ws_size,
                              hipStream_t stream) {
    const float* x  = (const float*)d_in[0];
    const float* cb = (const float*)d_in[1];
    float* out = (float*)d_out;

    unsigned short* cbsw = (unsigned short*)d_ws;
    double*         cc   = (double*)((char*)d_ws + (size_t)K_CODES * D_DIM * sizeof(unsigned short));

    hipLaunchKernelGGL(prep_cb, dim3(256), dim3(64),  0, stream, cb, cbsw, cc);
    hipLaunchKernelGGL(vq,      dim3(256), dim3(512), 0, stream, x, cb, cbsw, cc, out);
}